// Round 27
// baseline (82.972 us; speedup 1.0000x reference)
//
#include <hip/hip_runtime.h>
#include <hip/hip_bf16.h>

// HPBC step — R=4 adjacent outputs (FIR loads T+3 per row for 4 outputs) +
// 4-plane split sE (conflict-free 4tid-stride e-reads) + ±m shared G/H +
// template FIR + static double buffers + pk-FMA + parity-split gh.
// Geometry (solved): dict inputs, true complex assembly; output chunks
// [E' | Eo], element storage (IMAG, REAL) per (b, i', pol); nout=65436, lpad=50.

namespace {

constexpr int NSEQ    = 65536;
constexpr int BATCH   = 8;
constexpr int KTAPS   = 449;
constexpr int NM      = 25;
constexpr int THREADS = 256;
constexpr int TILE    = 1024;                    // 4 outputs/thread, adjacent
constexpr int WIN     = TILE + 4 * NM;           // 1124
constexpr int WINQ    = WIN / 4;                 // 281
constexpr int GHW     = TILE + 2 * NM + 1;       // 1075
constexpr int GHH     = (GHW + 1) / 2;           // 538

typedef float v2f __attribute__((ext_vector_type(2)));

__device__ inline v2f pkfma(float s, v2f v, v2f acc) {
  return __builtin_elementwise_fma((v2f){s, s}, v, acc);
}

__device__ inline void mac(v2f& U13, v2f& U42, v2f& V13, v2f& V42,
                           const float4 c, const float4 g) {
  const v2f glo = (v2f){g.x, g.y}, ghi = (v2f){g.z, g.w};
  U13 = pkfma(c.x, glo, U13); U42 = pkfma(c.y, glo, U42);
  V13 = pkfma(c.z, ghi, V13); V42 = pkfma(c.w, ghi, V42);
}

__device__ inline unsigned short f2bf(float f) {
  __hip_bfloat16 h = __float2bfloat16(f);
  union { __hip_bfloat16 hh; unsigned short u; } cv;
  cv.hh = h;
  return cv.u;
}

// cw[row*K+k] = (c1r,c1i,c2r,c2i); cw[4K + row*K+k] = (c2r,c2i,c1r,c1i)
__global__ void prep_c_kernel(const float* __restrict__ c1r, const float* __restrict__ c1i,
                              const float* __restrict__ c2r, const float* __restrict__ c2i,
                              float4* __restrict__ cw) {
  int idx = blockIdx.x * blockDim.x + threadIdx.x;
  if (idx < 4 * KTAPS) {
    cw[idx]             = make_float4(c1r[idx], c1i[idx], c2r[idx], c2i[idx]);
    cw[4 * KTAPS + idx] = make_float4(c2r[idx], c2i[idx], c1r[idx], c1i[idx]);
  }
}

__device__ inline float4 gh_entry(const float4 e, const float4 f,
                                  const float4 fm, const float4 em) {
  v2f G = (v2f){fm.w * e.w, fm.w * (-e.z)};
  G = pkfma(fm.x, (v2f){e.x, e.y}, G);
  G = pkfma(fm.y, (v2f){e.y, -e.x}, G);
  G = pkfma(fm.z, (v2f){e.z, e.w}, G);
  v2f H = (v2f){em.w * f.w, em.w * (-f.z)};
  H = pkfma(em.x, (v2f){f.x, f.y}, H);
  H = pkfma(em.y, (v2f){f.y, -f.x}, H);
  H = pkfma(em.z, (v2f){f.z, f.w}, H);
  return make_float4(G.x, G.y, H.x, H.y);
}

// 4-output FIR walk: outputs w..w+3 (w = 4*tid), taps t=0..T-1 read
// bi = 4tid + X - s where X = 28+nmax (+M for the minus pass); the load at
// step s feeds output r at tap t = s-3+r (guards compile-time).
// A0 = parity-(X&1) array, A1 = other; b0 = 2tid + (X>>1), b1 = 2tid + ((X-1)>>1).
template<int NMAX>
__device__ inline void fir4(const float4* __restrict__ A0, const float4* __restrict__ A1,
                            int b0, int b1, const float4* __restrict__ cc,
                            v2f* __restrict__ acc /* [16]: r*4 + {U13,U42,V13,V42} */)
{
  constexpr int T = 2 * NMAX + 1;
  float4 cw0, cw1, cw2, cw3;
#pragma unroll
  for (int s = 0; s <= T + 2; ++s) {
    const float4 g = (s & 1) ? A1[b1 - (s >> 1)] : A0[b0 - (s >> 1)];
    if (s < T) cw0 = cc[s];
    if (s <= T - 1)           mac(acc[12], acc[13], acc[14], acc[15], cw0, g);  // r=3, t=s
    if (s >= 1 && s <= T)     mac(acc[ 8], acc[ 9], acc[10], acc[11], cw1, g);  // r=2, t=s-1
    if (s >= 2 && s <= T + 1) mac(acc[ 4], acc[ 5], acc[ 6], acc[ 7], cw2, g);  // r=1, t=s-2
    if (s >= 3)               mac(acc[ 0], acc[ 1], acc[ 2], acc[ 3], cw3, g);  // r=0, t=s-3
    cw3 = cw2; cw2 = cw1; cw1 = cw0;
  }
}

#define FIR_SWITCH(NMX, A0_, A1_, B0_, B1_, CC, ACC) \
  switch (NMX) { \
    case 25: fir4<25>(A0_, A1_, B0_, B1_, CC, ACC); break; \
    case 12: fir4<12>(A0_, A1_, B0_, B1_, CC, ACC); break; \
    case  8: fir4< 8>(A0_, A1_, B0_, B1_, CC, ACC); break; \
    case  6: fir4< 6>(A0_, A1_, B0_, B1_, CC, ACC); break; \
    case  5: fir4< 5>(A0_, A1_, B0_, B1_, CC, ACC); break; \
    case  4: fir4< 4>(A0_, A1_, B0_, B1_, CC, ACC); break; \
    case  3: fir4< 3>(A0_, A1_, B0_, B1_, CC, ACC); break; \
    case  2: fir4< 2>(A0_, A1_, B0_, B1_, CC, ACC); break; \
    default: fir4< 1>(A0_, A1_, B0_, B1_, CC, ACC); break; \
  }

__global__ __launch_bounds__(THREADS, 2) void hpbc_kernel(
    const float2* __restrict__ er, const float2* __restrict__ ei,
    const float2* __restrict__ fr, const float2* __restrict__ fi,
    const float*  __restrict__ task, const float4* __restrict__ cw,
    unsigned short* __restrict__ out, int nout, int lpad, int ntiles)
{
  __shared__ float4 sE4[4][WINQ];   // E in 4-plane split: u -> [u&3][u>>2]
  __shared__ float4 sF[WIN];
  __shared__ float4 ghE0[GHH], ghO0[GHH];
  __shared__ float4 ghE1[GHH], ghO1[GHH];

  const int bx   = blockIdx.x;
  const int b    = bx / ntiles;
  const int tile = bx - b * ntiles;
  const int tid  = threadIdx.x;
  const int i0   = lpad + tile * TILE;
  const int elo  = i0 - 2 * NM;

  const float2* erb = er + (size_t)b * NSEQ;
  const float2* eib = ei + (size_t)b * NSEQ;
  const float2* frb = fr + (size_t)b * NSEQ;
  const float2* fib = fi + (size_t)b * NSEQ;

  for (int u = tid; u < WIN; u += THREADS) {
    int g = (elo + u) & (NSEQ - 1);                  // exact jnp.roll wrap
    float2 a = erb[g], c = eib[g];
    sE4[u & 3][u >> 2] = make_float4(a.x, c.x, a.y, c.y);
    float2 d = frb[g], e = fib[g];
    sF[u] = make_float4(d.x, e.x, d.y, e.y);
  }

  const float dbm = task[b * 4 + 0];
  const float fsr = task[b * 4 + 2];
  const int   x   = (int)(fsr / 2.0e9f);
  const int ind = (x == 40) ? 1 : (x == 80) ? 2 : (x == 160) ? 3 : 0;
  const float4* __restrict__ crow = cw + ind * KTAPS;
  const float4* __restrict__ cswp = cw + 4 * KTAPS + ind * KTAPS;
  const float P  = powf(10.0f, dbm * 0.1f) * 0.5f;
  const float pf = P * sqrtf(P);

  __syncthreads();

  // GH hoists: entries bi = tid + 256k (k=0..4); all k share one E-plane.
  const int pE = (tid + NM) & 3, iE = (tid + NM) >> 2;
  float4 eH[5], fH[5];
#pragma unroll
  for (int k = 0; k < 4; ++k) { eH[k] = sE4[pE][iE + 64 * k]; fH[k] = sF[tid + NM + 256 * k]; }
  const bool has5 = tid < GHW - 4 * THREADS;   // tid < 51
  if (has5) { eH[4] = sE4[pE][iE + 256]; fH[4] = sF[tid + NM + 1024]; }

  auto write_gh = [&](float4* wE, float4* wO, int Mn) {
    const int s  = NM - Mn;
    const int pS = (tid + s) & 3, iS = (tid + s) >> 2;
    const int wi = tid >> 1;
#pragma unroll
    for (int k = 0; k < 4; ++k) {
      const float4 fm = sF[tid + s + 256 * k];
      const float4 em = sE4[pS][iS + 64 * k];
      const float4 gk = gh_entry(eH[k], fH[k], fm, em);
      if (tid & 1) wO[wi + 128 * k] = gk; else wE[wi + 128 * k] = gk;
    }
    if (has5) {
      const float4 fm = sF[tid + s + 1024];
      const float4 em = sE4[pS][iS + 256];
      const float4 gk = gh_entry(eH[4], fH[4], fm, em);
      if (tid & 1) wO[wi + 512] = gk; else wE[wi + 512] = gk;
    }
  };

  v2f O0[4], O1[4];
#pragma unroll
  for (int r = 0; r < 4; ++r) { O0[r] = (v2f){0, 0}; O1[r] = (v2f){0, 0}; }
  int kbaseP = 199, kbaseN = 199;

  auto iter = [&](const float4* rE, const float4* rO,
                  float4* wE, float4* wO, int M) {
    const int nmax = (M == 0) ? NM : (NM / M);
    const int T    = 2 * nmax + 1;

    // ---- FIR(+M) ----
    {
      const int X = 28 + nmax;
      const float4* A0 = (X & 1) ? rO : rE;
      const float4* A1 = (X & 1) ? rE : rO;
      const int b0 = 2 * tid + (X >> 1);
      const int b1 = 2 * tid + ((X - 1) >> 1);
      v2f acc[16];
#pragma unroll
      for (int j = 0; j < 16; ++j) acc[j] = (v2f){0, 0};
      FIR_SWITCH(nmax, A0, A1, b0, b1, crow + kbaseP, acc);
      kbaseP += T;
#pragma unroll
      for (int r = 0; r < 4; ++r) {
        const float sr = acc[4*r].x - acc[4*r+1].y + acc[4*r+2].x - acc[4*r+3].y;
        const float si = acc[4*r].y + acc[4*r+1].x + acc[4*r+2].y + acc[4*r+3].x;
        const int u = 4 * tid + r + 2 * NM - M;
        const float4 e = sE4[u & 3][u >> 2];
        O0[r] = pkfma(sr, (v2f){e.x, e.y}, pkfma(si, (v2f){-e.y, e.x}, O0[r]));
        O1[r] = pkfma(sr, (v2f){e.z, e.w}, pkfma(si, (v2f){-e.w, e.z}, O1[r]));
      }
    }

    // ---- FIR(-M): shared buffer, base +M, swapped-c, conj reduction ----
    if (M > 0) {
      kbaseN -= T;
      const int X = 28 + nmax + M;
      const float4* A0 = (X & 1) ? rO : rE;
      const float4* A1 = (X & 1) ? rE : rO;
      const int b0 = 2 * tid + (X >> 1);
      const int b1 = 2 * tid + ((X - 1) >> 1);
      v2f acc[16];
#pragma unroll
      for (int j = 0; j < 16; ++j) acc[j] = (v2f){0, 0};
      FIR_SWITCH(nmax, A0, A1, b0, b1, cswp + kbaseN, acc);
#pragma unroll
      for (int r = 0; r < 4; ++r) {
        const float sr = acc[4*r].x + acc[4*r+1].y + acc[4*r+2].x + acc[4*r+3].y;
        const float si = acc[4*r+1].x - acc[4*r].y + acc[4*r+3].x - acc[4*r+2].y;
        const int u = 4 * tid + r + 2 * NM + M;
        const float4 e = sE4[u & 3][u >> 2];
        O0[r] = pkfma(sr, (v2f){e.x, e.y}, pkfma(si, (v2f){-e.y, e.x}, O0[r]));
        O1[r] = pkfma(sr, (v2f){e.z, e.w}, pkfma(si, (v2f){-e.w, e.z}, O1[r]));
      }
    }

    if (M < NM) write_gh(wE, wO, M + 1);
    __syncthreads();
  };

  // Prologue: GH(order 0) into buffer 0.
  write_gh(ghE0, ghO0, 0);
  __syncthreads();

  for (int M = 0; M <= NM; M += 2) {
    iter(ghE0, ghO0, ghE1, ghO1, M);
    if (M + 1 <= NM)
      iter(ghE1, ghO1, ghE0, ghO0, M + 1);
  }

  // ---- Epilogue: (IMAG, REAL) element order ----
  const int end = lpad + nout;
  const size_t chunk1 = (size_t)BATCH * nout * 4;
#pragma unroll
  for (int r = 0; r < 4; ++r) {
    const int ii = 4 * tid + r;
    const int i  = i0 + ii;
    if (i < end) {
      const int u = ii + 2 * NM;
      const float4 ev = sE4[u & 3][u >> 2];
      const float4 fv = sF[u];
      const size_t o = ((size_t)b * nout + (size_t)(i - lpad)) * 4;
      ushort4 w0, w1;
      w0.x = f2bf(ev.y); w0.y = f2bf(ev.x); w0.z = f2bf(ev.w); w0.w = f2bf(ev.z);
      w1.x = f2bf(fv.y + pf * O0[r].y); w1.y = f2bf(fv.x + pf * O0[r].x);
      w1.z = f2bf(fv.w + pf * O1[r].y); w1.w = f2bf(fv.z + pf * O1[r].x);
      *reinterpret_cast<ushort4*>(out + o) = w0;
      *reinterpret_cast<ushort4*>(out + chunk1 + o) = w1;
    }
  }
}

} // namespace

extern "C" void kernel_launch(void* const* d_in, const int* in_sizes, int n_in,
                              void* d_out, int out_size, void* d_ws, size_t ws_size,
                              hipStream_t stream) {
  const float* E_real  = (const float*)d_in[0];
  const float* E_imag  = (const float*)d_in[1];
  const float* F_real  = (const float*)d_in[2];
  const float* F_imag  = (const float*)d_in[3];
  const float* C1_real = (const float*)d_in[4];
  const float* C1_imag = (const float*)d_in[5];
  const float* C2_real = (const float*)d_in[6];
  const float* C2_imag = (const float*)d_in[7];
  const float* task    = (const float*)d_in[8];

  int nout = out_size / 32;
  if (nout < 1 || nout > NSEQ) nout = NSEQ - 100;
  const int lpad   = (NSEQ - nout) / 2;             // 50
  const int ntiles = (nout + TILE - 1) / TILE;      // 64

  unsigned short* outp = (unsigned short*)d_out;
  float4* cw = (float4*)d_ws;                       // 2 tables: 57,472 B

  hipLaunchKernelGGL(prep_c_kernel, dim3((4 * KTAPS + 255) / 256), dim3(256), 0, stream,
                     C1_real, C1_imag, C2_real, C2_imag, cw);

  hipLaunchKernelGGL(hpbc_kernel, dim3(BATCH * ntiles), dim3(THREADS), 0, stream,
                     (const float2*)E_real, (const float2*)E_imag,
                     (const float2*)F_real, (const float2*)F_imag,
                     task, cw, outp, nout, lpad, ntiles);
}